// Round 2
// baseline (485.785 us; speedup 1.0000x reference)
//
#include <hip/hip_runtime.h>
#include <type_traits>

// Problem constants
#define N_ATOMS 512
#define C_DIM   64
#define K_SP    5
#define TS      16      // signals per block
#define HSTR    20      // H LDS row stride in floats (16 + 4 pad, keeps float4 align)

// ws layout (floats):
//   dn   [0,      32768)   : (64 x 512) row-major [c][n]
//   dnT  [32768,  65536)   : (512 x 64) [n][c]
//   G    [65536, 327680)   : (512 x 512)
//   lossAcc (double) at byte offset 327680*4 = 1310720

// ---------------------------------------------------------------------------
// Kernel 1: column norms + normalized dictionary (dn) + its transpose (dnT).
// Mimics numpy: squares rounded individually, sequential sum over c, f32 sqrt,
// d / max(m, eps).
// ---------------------------------------------------------------------------
__global__ __launch_bounds__(256) void prep_norm_k(const float* __restrict__ dict,
                                                   float* __restrict__ dn,
                                                   float* __restrict__ dnT,
                                                   double* __restrict__ lossAcc) {
#pragma clang fp contract(off)
  const int n = blockIdx.x * 256 + threadIdx.x;
  if (blockIdx.x == 0 && threadIdx.x == 0) *lossAcc = 0.0;
  if (n >= N_ATOMS) return;
  float s = 0.0f;
  for (int c = 0; c < C_DIM; ++c) {
    float v = dict[c * N_ATOMS + n];
    float sq = v * v;
    s = s + sq;
  }
  float m = fmaxf(sqrtf(s), 1e-10f);
  for (int c = 0; c < C_DIM; ++c) {
    float q = dict[c * N_ATOMS + n] / m;
    dn[c * N_ATOMS + n] = q;
    dnT[n * C_DIM + c] = q;
  }
}

// ---------------------------------------------------------------------------
// Kernel 2: G = dn^T dn (512x512), f32 FMA chain sequential over c (BLAS-like
// k-ascending single-accumulator order).
// ---------------------------------------------------------------------------
__global__ __launch_bounds__(256) void prep_gram_k(const float* __restrict__ dn,
                                                   float* __restrict__ G) {
#pragma clang fp contract(off)
  __shared__ float As[64][64];
  __shared__ float Bs[64][64];
  const int bi = blockIdx.x & 7, bj = blockIdx.x >> 3;
  const int tid = threadIdx.x;
  for (int r = 0; r < 16; ++r) {
    int e = r * 256 + tid;
    int c = e >> 6, i = e & 63;
    As[c][i] = dn[c * N_ATOMS + bi * 64 + i];
    Bs[c][i] = dn[c * N_ATOMS + bj * 64 + i];
  }
  __syncthreads();
  const int ti = tid & 15, tj = tid >> 4;
  float acc[4][4] = {};
  for (int c = 0; c < 64; ++c) {
    float a[4], b[4];
#pragma unroll
    for (int u = 0; u < 4; ++u) { a[u] = As[c][ti * 4 + u]; b[u] = Bs[c][tj * 4 + u]; }
#pragma unroll
    for (int u = 0; u < 4; ++u)
#pragma unroll
      for (int v = 0; v < 4; ++v) acc[u][v] = fmaf(a[u], b[v], acc[u][v]);
  }
  for (int u = 0; u < 4; ++u)
    for (int v = 0; v < 4; ++v)
      G[(size_t)(bi * 64 + ti * 4 + u) * N_ATOMS + bj * 64 + tj * 4 + v] = acc[u][v];
}

// ---------------------------------------------------------------------------
// Kernel 3: fused h_bar GEMM + batched OMP + outputs.
// Block = 16 signals (same b, 16 consecutive hw). 256 threads = 4 waves.
// Phase 1: H[512][16] = dn^T * X  (register-blocked, dn chunk-staged in LDS)
// Phase 2: per-wave OMP, 4 signals each (lane = atoms {lane + 64*jb})
// Phase 3: coeffs zero+scatter for the block's 16 columns.
// ---------------------------------------------------------------------------
__global__ __launch_bounds__(256) void omp_main_k(const float* __restrict__ z,
                                                  const float* __restrict__ dn,
                                                  const float* __restrict__ dnT,
                                                  const float* __restrict__ Gm,
                                                  float* __restrict__ out0,
                                                  float* __restrict__ coeffs,
                                                  double* __restrict__ lossAcc) {
#pragma clang fp contract(off)
  __shared__ float Xs[64][16];                       // 4 KB  : Xs[c][sl]
  __shared__ __align__(16) float UB[N_ATOMS * HSTR]; // 40 KB : DnChunk then H
  __shared__ int   IldsI[TS][K_SP];
  __shared__ float IldsX[TS][K_SP];

  const int tid   = threadIdx.x;
  const int sbase = blockIdx.x * TS;
  const int b     = sbase >> 10;
  const int hw0   = sbase & 1023;
  const float* zb = z + (size_t)b * 65536;

  // ---- stage Xs (coalesced float4) ----
  {
    int c = tid >> 2, slc = (tid & 3) * 4;
    float4 v = *reinterpret_cast<const float4*>(zb + c * 1024 + hw0 + slc);
    *reinterpret_cast<float4*>(&Xs[c][slc]) = v;
  }

  // ---- Phase 1: GEMM. thread: atoms {4*ia+r, 256+4*ia+r}, signals {4*js+u}
  const int ia4 = (tid & 63) * 4;
  const int js4 = (tid >> 6) * 4;
  float acc[8][4] = {};
#pragma unroll
  for (int cc = 0; cc < 4; ++cc) {
    __syncthreads();
    {
      const float* src = dn + cc * 8192;   // 16 rows x 512
#pragma unroll
      for (int r = 0; r < 8; ++r) {
        int off = (r * 256 + tid) * 4;
        *reinterpret_cast<float4*>(&UB[off]) = *reinterpret_cast<const float4*>(src + off);
      }
    }
    __syncthreads();
#pragma unroll
    for (int c = 0; c < 16; ++c) {
      const float4 xv = *reinterpret_cast<const float4*>(&Xs[cc * 16 + c][js4]);
      const float4 d0 = *reinterpret_cast<const float4*>(&UB[c * 512 + ia4]);
      const float4 d1 = *reinterpret_cast<const float4*>(&UB[c * 512 + 256 + ia4]);
      const float dv[8] = { d0.x, d0.y, d0.z, d0.w, d1.x, d1.y, d1.z, d1.w };
      const float xw[4] = { xv.x, xv.y, xv.z, xv.w };
#pragma unroll
      for (int r = 0; r < 8; ++r)
#pragma unroll
        for (int u = 0; u < 4; ++u)
          acc[r][u] = fmaf(dv[r], xw[u], acc[r][u]);   // sequential over global c
    }
  }
  __syncthreads();
  // write H into UB (reinterpreted as [512][HSTR])
#pragma unroll
  for (int r = 0; r < 8; ++r) {
    int n = (r < 4) ? (ia4 + r) : (256 + ia4 + (r - 4));
    *reinterpret_cast<float4*>(&UB[n * HSTR + js4]) =
        make_float4(acc[r][0], acc[r][1], acc[r][2], acc[r][3]);
  }
  __syncthreads();

  // ---- Phase 2: OMP (wave per signal, 4 signals per wave) ----
  const int lane = tid & 63;
  const int wid  = tid >> 6;
  double lsum = 0.0;

  for (int q = 0; q < 4; ++q) {
    const int sl = wid * 4 + q;
    float hb[8];
#pragma unroll
    for (int jb = 0; jb < 8; ++jb) hb[jb] = UB[(lane + 64 * jb) * HSTR + sl];

    unsigned selmask = 0;
    int   I[K_SP];
    float xs[K_SP];
    float hstk[K_SP];
    float Lm[K_SP][K_SP];
    int   srtI[4];
    float GrowS[4][8];

    auto iter = [&](auto KC) {
      constexpr int k = decltype(KC)::value;
      float cur[8];
      if constexpr (k == 1) {
#pragma unroll
        for (int jb = 0; jb < 8; ++jb) cur[jb] = hb[jb];
      } else {
        // xs values aligned to sorted atom order (numpy sums beta in j-ascending order)
        float xsS[k - 1];
#pragma unroll
        for (int u = 0; u < k - 1; ++u) {
          float xv = 0.0f;
#pragma unroll
          for (int t = 0; t < k - 1; ++t) xv = (I[t] == srtI[u]) ? xs[t] : xv;
          xsS[u] = xv;
        }
#pragma unroll
        for (int jb = 0; jb < 8; ++jb) {
          float beta = 0.0f;
#pragma unroll
          for (int u = 0; u < k - 1; ++u) beta = fmaf(xsS[u], GrowS[u][jb], beta);
          cur[jb] = hb[jb] - beta;
        }
      }
      // masked |.| argmax, first-index tie-break (numpy argmax semantics)
      float bv = -1.0f; int bn = 1 << 30;
#pragma unroll
      for (int jb = 0; jb < 8; ++jb) {
        float v = ((selmask >> jb) & 1u) ? 0.0f : fabsf(cur[jb]);
        int n = lane + 64 * jb;
        bool better = (v > bv) || ((v == bv) && (n < bn));
        bv = better ? v : bv; bn = better ? n : bn;
      }
#pragma unroll
      for (int m = 1; m < 64; m <<= 1) {
        float ov = __shfl_xor(bv, m, 64);
        int   on = __shfl_xor(bn, m, 64);
        bool better = (ov > bv) || ((ov == bv) && (on < bn));
        bv = better ? ov : bv; bn = better ? on : bn;
      }
      const int nsel = bn;
      I[k - 1] = nsel;
      if ((nsel & 63) == lane) selmask |= (1u << (nsel >> 6));

      if constexpr (k > 1) {
        float Gs[k - 1], w[k - 1];
#pragma unroll
        for (int t = 0; t < k - 1; ++t) Gs[t] = Gm[(size_t)I[t] * N_ATOMS + nsel];
#pragma unroll
        for (int t = 0; t < k - 1; ++t) {
          float a = Gs[t];
#pragma unroll
          for (int u = 0; u < t; ++u) a = a - Lm[t][u] * w[u];
          w[t] = a / Lm[t][t];
        }
        float ss = 0.0f;
#pragma unroll
        for (int t = 0; t < k - 1; ++t) { float sq = w[t] * w[t]; ss = ss + sq; }
        float wc = sqrtf(1.0f - ss);
#pragma unroll
        for (int t = 0; t < k - 1; ++t) Lm[k - 1][t] = w[t];
        Lm[k - 1][k - 1] = wc;
      } else {
        Lm[0][0] = 1.0f;
      }
      hstk[k - 1] = UB[nsel * HSTR + sl];
      float y[k];
#pragma unroll
      for (int t = 0; t < k; ++t) {
        float a = hstk[t];
#pragma unroll
        for (int u = 0; u < t; ++u) a = a - Lm[t][u] * y[u];
        y[t] = a / Lm[t][t];
      }
#pragma unroll
      for (int t = k - 1; t >= 0; --t) {
        float a = y[t];
#pragma unroll
        for (int u = t + 1; u < k; ++u) a = a - Lm[u][t] * xs[u];
        xs[t] = a / Lm[t][t];
      }
      if constexpr (k <= 4) {
        // load G row of nsel (coalesced) and insert sorted by atom id
        float nr[8];
#pragma unroll
        for (int jb = 0; jb < 8; ++jb) nr[jb] = Gm[(size_t)nsel * N_ATOMS + lane + 64 * jb];
        int p = 0;
#pragma unroll
        for (int u = 0; u < k - 1; ++u) p += (srtI[u] < nsel) ? 1 : 0;
#pragma unroll
        for (int u = k - 1; u >= 1; --u) {
          bool tp = (u > p);
          srtI[u] = tp ? srtI[u - 1] : srtI[u];
#pragma unroll
          for (int jb = 0; jb < 8; ++jb) GrowS[u][jb] = tp ? GrowS[u - 1][jb] : GrowS[u][jb];
        }
#pragma unroll
        for (int u = 0; u < k; ++u) {
          bool at = (u == p);
          srtI[u] = at ? nsel : srtI[u];
#pragma unroll
          for (int jb = 0; jb < 8; ++jb) GrowS[u][jb] = at ? nr[jb] : GrowS[u][jb];
        }
      }
    };
    iter(std::integral_constant<int, 1>{});
    iter(std::integral_constant<int, 2>{});
    iter(std::integral_constant<int, 3>{});
    iter(std::integral_constant<int, 4>{});
    iter(std::integral_constant<int, 5>{});

    if (lane == 0) {
#pragma unroll
      for (int t = 0; t < K_SP; ++t) { IldsI[sl][t] = I[t]; IldsX[sl][t] = xs[t]; }
    }

    // recon in sorted-index order (numpy GEMM sums j ascending)
    int sI[5]; float sX[5];
#pragma unroll
    for (int t = 0; t < 5; ++t) { sI[t] = I[t]; sX[t] = xs[t]; }
#pragma unroll
    for (int a = 0; a < 4; ++a)
#pragma unroll
      for (int t = 0; t < 4 - a; ++t) {
        bool sw = sI[t] > sI[t + 1];
        int   i0 = sw ? sI[t + 1] : sI[t];
        int   i1 = sw ? sI[t] : sI[t + 1];
        float x0 = sw ? sX[t + 1] : sX[t];
        float x1 = sw ? sX[t] : sX[t + 1];
        sI[t] = i0; sI[t + 1] = i1; sX[t] = x0; sX[t + 1] = x1;
      }
    float r = 0.0f;
#pragma unroll
    for (int t = 0; t < 5; ++t) r = fmaf(sX[t], dnT[(size_t)sI[t] * C_DIM + lane], r);
    float ze = Xs[lane][sl];
    float t1 = r - ze;                          // z_dl - z_e (rounded, as reference)
    out0[(size_t)b * 65536 + lane * 1024 + hw0 + sl] = ze + t1;   // z_dl_st
    float sq = t1 * t1;
    lsum += (double)sq;
  }

  // wave loss reduce + one atomic per wave
#pragma unroll
  for (int m = 1; m < 64; m <<= 1) lsum += __shfl_xor(lsum, m, 64);
  if (lane == 0) atomicAdd(lossAcc, lsum);

  // ---- Phase 3: coeffs zero + scatter for this block's 16 columns ----
  __syncthreads();
  {
    int rbase = tid >> 2;
    int c0 = (tid & 3) * 4;
#pragma unroll
    for (int p = 0; p < 8; ++p) {
      int rown = p * 64 + rbase;
      float v[4];
#pragma unroll
      for (int u = 0; u < 4; ++u) {
        int slc = c0 + u;
        float val = 0.0f;
#pragma unroll
        for (int t = 0; t < K_SP; ++t)
          val = (IldsI[slc][t] == rown) ? IldsX[slc][t] : val;
        v[u] = val;
      }
      size_t base = (size_t)rown * 65536 + sbase + c0;
      coeffs[base + 0] = v[0];
      coeffs[base + 1] = v[1];
      coeffs[base + 2] = v[2];
      coeffs[base + 3] = v[3];
    }
  }
}

// ---------------------------------------------------------------------------
// Kernel 4: finalize loss
// ---------------------------------------------------------------------------
__global__ void finalize_k(const double* __restrict__ lossAcc, float* __restrict__ out) {
  if (threadIdx.x == 0) {
    float dl = (float)(*lossAcc / 4194304.0);
    out[4194304] = dl + 0.25f * dl;
  }
}

extern "C" void kernel_launch(void* const* d_in, const int* in_sizes, int n_in,
                              void* d_out, int out_size, void* d_ws, size_t ws_size,
                              hipStream_t stream) {
  (void)in_sizes; (void)n_in; (void)out_size; (void)ws_size;
  const float* z    = (const float*)d_in[0];   // (64,64,32,32)
  const float* dict = (const float*)d_in[1];   // (64,512)
  float* out    = (float*)d_out;               // z_dl_st | loss | coeffs
  float* coeffs = out + 4194305;
  float* dn  = (float*)d_ws;
  float* dnT = dn + 32768;
  float* G   = dnT + 32768;
  double* lossAcc = (double*)((char*)d_ws + 1310720);

  prep_norm_k<<<2, 256, 0, stream>>>(dict, dn, dnT, lossAcc);
  prep_gram_k<<<64, 256, 0, stream>>>(dn, G);
  omp_main_k<<<4096, 256, 0, stream>>>(z, dn, dnT, G, out, coeffs, lossAcc);
  finalize_k<<<1, 64, 0, stream>>>(lossAcc, out);
}